// Round 1
// baseline (1704.711 us; speedup 1.0000x reference)
//
#include <hip/hip_runtime.h>
#include <cstdint>

#define HW 3136
#define WID 56

__device__ __forceinline__ int clampi(int v, int lo, int hi) {
    return v < lo ? lo : (v > hi ? hi : v);
}

// Fused: corr (stage1) -> W (stage2) -> weighted gather acc (stage3) + per-block BN partials.
// One thread per pixel; block = 4 rows x 56 cols of one frame-pair; grid = 32*14 = 448.
__global__ __launch_bounds__(256, 2) void tf_fused(
    const float* __restrict__ x, const float* __restrict__ wconv,
    const float* __restrict__ bconv, float* __restrict__ out,
    float* __restrict__ psum, float* __restrict__ psumsq)
{
    // ch-innermost tiles padded to stride 12 floats (48B): b128 reads conflict-free & aligned
    __shared__ float tile[2][6][58][12];
    __shared__ float sred[8][264];

    const int blk = blockIdx.x;
    const int n = blk / 14;
    const int r0 = (blk % 14) * 4;
    const int t = threadIdx.x;
    const int wv = t >> 6;            // wave id == thread-row 0..3
    const int lane = t & 63;
    const bool act = lane < WID;
    const int col = act ? lane : (WID - 1);  // clamped for safe LDS reads
    const int r = r0 + wv;

    const float* xe = x + (size_t)(2 * n) * 256 * HW;  // even frame 2n
    const float* xo = xe + (size_t)256 * HW;           // odd frame 2n+1

    // ---------------- stage 1: corr[ij*8+g] = sum_ch e(p)*o(p+delta) ----------------
    float cr[72];
    #pragma unroll
    for (int i = 0; i < 72; ++i) cr[i] = 0.f;

    {   // stage odd chunk 0 into buf 0
        for (int s = wv; s < 48; s += 4) {
            const int tr = s >> 3, cc = s & 7;
            if (lane < 58) {
                const int sr = clampi(r0 + tr - 1, 0, 55);
                const int sc = clampi(lane - 1, 0, 55);
                tile[0][tr][lane][cc] = xo[(size_t)cc * HW + sr * WID + sc];
            }
        }
    }
    __syncthreads();

    #pragma unroll
    for (int g = 0; g < 8; ++g) {          // g = ch>>5 (compile-time for cr index)
        for (int sub = 0; sub < 4; ++sub) {
            const int q = g * 4 + sub;
            const int buf = q & 1;
            // prefetch next chunk into the other buffer
            if (q < 31) {
                const int ch0n = (q + 1) * 8;
                for (int s = wv; s < 48; s += 4) {
                    const int tr = s >> 3, cc = s & 7;
                    if (lane < 58) {
                        const int sr = clampi(r0 + tr - 1, 0, 55);
                        const int sc = clampi(lane - 1, 0, 55);
                        tile[buf ^ 1][tr][lane][cc] =
                            xo[(size_t)(ch0n + cc) * HW + sr * WID + sc];
                    }
                }
            }
            // compute current chunk
            const int ch0 = q * 8;
            float e[8];
            #pragma unroll
            for (int cc = 0; cc < 8; ++cc)
                e[cc] = act ? xe[(size_t)(ch0 + cc) * HW + r * WID + lane] : 0.f;
            #pragma unroll
            for (int di = 0; di < 3; ++di)
                #pragma unroll
                for (int dj = 0; dj < 3; ++dj) {
                    const float* p = &tile[buf][wv + di][col + dj][0];
                    const float4 o0 = *(const float4*)p;
                    const float4 o1 = *(const float4*)(p + 4);
                    float ssum = e[0] * o0.x + e[1] * o0.y + e[2] * o0.z + e[3] * o0.w
                               + e[4] * o1.x + e[5] * o1.y + e[6] * o1.z + e[7] * o1.w;
                    cr[(di * 3 + dj) * 8 + g] += ssum;
                }
            __syncthreads();
        }
    }

    // ---------------- stage 2: W[f] = b[f] + sum_b cr[(f/18)*9+b]*wconv[f*9+b] ----------------
    // wconv/bconv addresses are wave-uniform -> scalar loads
    float Wv[144];
    #pragma unroll
    for (int f = 0; f < 144; ++f) {
        float s = bconv[f];
        const int a = f / 18;
        #pragma unroll
        for (int b2 = 0; b2 < 9; ++b2) s += cr[a * 9 + b2] * wconv[f * 9 + b2];
        Wv[f] = s;
    }

    // ---------------- stage 3: acc(ch) = sum_ij e*W[ij*16+2g] + o*W[ij*16+2g+1], g=ch&7 ----------------
    for (int q = 0; q < 32; ++q) {
        const int ch0 = q * 8;
        // stage both frames, 96 slabs of 58
        for (int s = wv; s < 96; s += 4) {
            const int fr = s / 48;
            const int rm = s - fr * 48;
            const int tr = rm >> 3, cc = rm & 7;
            if (lane < 58) {
                const int sr = clampi(r0 + tr - 1, 0, 55);
                const int sc = clampi(lane - 1, 0, 55);
                const float* src = fr ? xo : xe;
                tile[fr][tr][lane][cc] = src[(size_t)(ch0 + cc) * HW + sr * WID + sc];
            }
        }
        __syncthreads();

        float acc[8];
        #pragma unroll
        for (int cc = 0; cc < 8; ++cc) acc[cc] = 0.f;
        #pragma unroll
        for (int di = 0; di < 3; ++di)
            #pragma unroll
            for (int dj = 0; dj < 3; ++dj) {
                const int ij = di * 3 + dj;
                const float* pe = &tile[0][wv + di][col + dj][0];
                const float* po = &tile[1][wv + di][col + dj][0];
                const float4 e0 = *(const float4*)pe;
                const float4 e1 = *(const float4*)(pe + 4);
                const float4 o0 = *(const float4*)po;
                const float4 o1 = *(const float4*)(po + 4);
                acc[0] += e0.x * Wv[ij * 16 + 0]  + o0.x * Wv[ij * 16 + 1];
                acc[1] += e0.y * Wv[ij * 16 + 2]  + o0.y * Wv[ij * 16 + 3];
                acc[2] += e0.z * Wv[ij * 16 + 4]  + o0.z * Wv[ij * 16 + 5];
                acc[3] += e0.w * Wv[ij * 16 + 6]  + o0.w * Wv[ij * 16 + 7];
                acc[4] += e1.x * Wv[ij * 16 + 8]  + o1.x * Wv[ij * 16 + 9];
                acc[5] += e1.y * Wv[ij * 16 + 10] + o1.y * Wv[ij * 16 + 11];
                acc[6] += e1.z * Wv[ij * 16 + 12] + o1.z * Wv[ij * 16 + 13];
                acc[7] += e1.w * Wv[ij * 16 + 14] + o1.w * Wv[ij * 16 + 15];
            }
        #pragma unroll
        for (int cc = 0; cc < 8; ++cc) {
            if (act) out[((size_t)n * 256 + ch0 + cc) * HW + r * WID + lane] = acc[cc];
            sred[cc][t] = act ? acc[cc] : 0.f;
        }
        __syncthreads();
        {   // per-(block, channel) partial sum / sumsq, deterministic tree
            const int c2 = t >> 5, sg = t & 31;
            const float4 v0 = *(const float4*)&sred[c2][sg * 8];
            const float4 v1 = *(const float4*)&sred[c2][sg * 8 + 4];
            float s  = v0.x + v0.y + v0.z + v0.w + v1.x + v1.y + v1.z + v1.w;
            float qq = v0.x * v0.x + v0.y * v0.y + v0.z * v0.z + v0.w * v0.w
                     + v1.x * v1.x + v1.y * v1.y + v1.z * v1.z + v1.w * v1.w;
            #pragma unroll
            for (int o = 16; o >= 1; o >>= 1) {
                s  += __shfl_xor(s, o);
                qq += __shfl_xor(qq, o);
            }
            if (sg == 0) {
                psum  [(ch0 + c2) * 448 + blk] = s;
                psumsq[(ch0 + c2) * 448 + blk] = qq;
            }
        }
        __syncthreads();
    }
}

__global__ void tf_stats(const float* __restrict__ ps, const float* __restrict__ pq,
                         const float* __restrict__ gamma, const float* __restrict__ beta,
                         float* __restrict__ AB)
{
    const int ch = blockIdx.x;
    const int l = threadIdx.x;
    float s = 0.f, q = 0.f;
    for (int b = l; b < 448; b += 64) {
        s += ps[ch * 448 + b];
        q += pq[ch * 448 + b];
    }
    #pragma unroll
    for (int o = 32; o >= 1; o >>= 1) {
        s += __shfl_xor(s, o);
        q += __shfl_xor(q, o);
    }
    if (l == 0) {
        const float inv = 1.f / 100352.f;   // nt2*h*w
        const float mean = s * inv;
        const float var = q * inv - mean * mean;
        const float rstd = rsqrtf(var + 1e-5f);
        const float A = gamma[ch] * rstd;
        AB[ch] = A;
        AB[256 + ch] = beta[ch] - mean * A;
    }
}

__global__ void tf_norm(float* __restrict__ out, const float* __restrict__ AB)
{
    const unsigned total4 = 32u * 256u * 784u;  // 6,422,528 float4
    unsigned i = blockIdx.x * 256u + threadIdx.x;
    const unsigned stride = gridDim.x * 256u;
    float4* o4 = (float4*)out;
    for (; i < total4; i += stride) {
        const unsigned ch = (i / 784u) & 255u;
        const float A = AB[ch], B = AB[256 + ch];
        float4 v = o4[i];
        v.x = v.x * A + B;
        v.y = v.y * A + B;
        v.z = v.z * A + B;
        v.w = v.w * A + B;
        o4[i] = v;
    }
}

extern "C" void kernel_launch(void* const* d_in, const int* in_sizes, int n_in,
                              void* d_out, int out_size, void* d_ws, size_t ws_size,
                              hipStream_t stream) {
    const float* x     = (const float*)d_in[0];
    const float* wconv = (const float*)d_in[1];
    const float* bconv = (const float*)d_in[2];
    const float* gamma = (const float*)d_in[3];
    const float* beta  = (const float*)d_in[4];
    float* out = (float*)d_out;

    float* psum   = (float*)d_ws;            // [256][448]
    float* psumsq = psum + 256 * 448;        // [256][448]
    float* AB     = psumsq + 256 * 448;      // [512]

    tf_fused<<<448, 256, 0, stream>>>(x, wconv, bconv, out, psum, psumsq);
    tf_stats<<<256, 64, 0, stream>>>(psum, psumsq, gamma, beta, AB);
    tf_norm<<<2048, 256, 0, stream>>>(out, AB);
}

// Round 2
// 1178.909 us; speedup vs baseline: 1.4460x; 1.4460x over previous
//
#include <hip/hip_runtime.h>
#include <cstdint>

#define HW 3136
#define WID 56

__device__ __forceinline__ int clampi(int v, int lo, int hi) {
    return v < lo ? lo : (v > hi ? hi : v);
}

// Fused: corr (stage1, folded immediately into W) -> weighted gather acc (stage3)
// + per-block BN partials. One thread per pixel; block = 4 rows x 56 cols of one
// frame-pair; grid = 32*14 = 448.
// Register budget: Wv[144] + crg[9] + temps ~ 190 VGPR -> (256,1) so no 128 cap/spill.
__global__ __launch_bounds__(256, 1) void tf_fused(
    const float* __restrict__ x, const float* __restrict__ wconv,
    const float* __restrict__ bconv, float* __restrict__ out,
    float* __restrict__ psum, float* __restrict__ psumsq)
{
    // ch-innermost tiles padded to stride 12 floats (48B): b128 read/write hit all
    // 32 banks per 8 lanes -> conflict-free, 16B-aligned.
    __shared__ float tile[2][6][58][12];
    __shared__ float sred[8][264];   // 264 = 256+8: rows 8 banks apart

    const int blk = blockIdx.x;
    const int n = blk / 14;
    const int r0 = (blk % 14) * 4;
    const int t = threadIdx.x;
    const int wv = t >> 6;            // wave id == thread-row 0..3
    const int lane = t & 63;
    const bool act = lane < WID;
    const int col = act ? lane : (WID - 1);  // clamped for safe LDS reads
    const int r = r0 + wv;

    const float* xe = x + (size_t)(2 * n) * 256 * HW;  // even frame 2n
    const float* xo = xe + (size_t)256 * HW;           // odd frame 2n+1

    // staging halo geometry (q-invariant)
    const int sc = clampi(lane - 1, 0, 55);
    int srow[6];
    #pragma unroll
    for (int tr = 0; tr < 6; ++tr) srow[tr] = clampi(r0 + tr - 1, 0, 55) * WID + sc;

    // W accumulator, init with bias (scalar loads)
    float Wv[144];
    #pragma unroll
    for (int f = 0; f < 144; ++f) Wv[f] = bconv[f];

    // ---- stage odd-frame 8-channel chunk into tile[buf] : 12 slabs (tr, half4) ----
    auto stage_odd = [&](int buf, int ch0) {
        #pragma unroll
        for (int k = 0; k < 3; ++k) {
            const int s = wv + 4 * k;          // 0..11
            const int tr = s >> 1, half = s & 1;
            if (lane < 58) {
                const float* src = xo + (size_t)(ch0 + half * 4) * HW + srow[tr];
                float4 v;
                v.x = src[0]; v.y = src[HW]; v.z = src[2 * HW]; v.w = src[3 * HW];
                *(float4*)&tile[buf][tr][lane][half * 4] = v;
            }
        }
    };

    // ---------------- stage 1: corr, folded into Wv per channel-group ----------------
    const float* xer = xe + r * WID + lane;   // per-thread even-pixel base (garbage ok for lane>=56)

    stage_odd(0, 0);
    __syncthreads();

    #pragma unroll
    for (int g = 0; g < 8; ++g) {            // g = ch>>5
        float crg[9];
        #pragma unroll
        for (int i = 0; i < 9; ++i) crg[i] = 0.f;

        #pragma unroll
        for (int sub = 0; sub < 4; ++sub) {
            const int q = g * 4 + sub;
            const int buf = q & 1;
            if (q < 31) stage_odd(buf ^ 1, (q + 1) * 8);

            const int ch0 = q * 8;
            float e[8];
            #pragma unroll
            for (int cc = 0; cc < 8; ++cc) e[cc] = xer[(size_t)(ch0 + cc) * HW];

            #pragma unroll
            for (int di = 0; di < 3; ++di)
                #pragma unroll
                for (int dj = 0; dj < 3; ++dj) {
                    const float* p = &tile[buf][wv + di][col + dj][0];
                    const float4 o0 = *(const float4*)p;
                    const float4 o1 = *(const float4*)(p + 4);
                    crg[di * 3 + dj] +=
                          e[0] * o0.x + e[1] * o0.y + e[2] * o0.z + e[3] * o0.w
                        + e[4] * o1.x + e[5] * o1.y + e[6] * o1.z + e[7] * o1.w;
                }
            __syncthreads();
        }
        // fold: flat corr index F=ij*8+g is consumed at (a,b)=(F/9,F%9) of the matvec
        #pragma unroll
        for (int ij = 0; ij < 9; ++ij) {
            const int F = ij * 8 + g, a = F / 9, b = F % 9;
            const float c = crg[ij];
            #pragma unroll
            for (int o = 0; o < 18; ++o)
                Wv[a * 18 + o] += c * wconv[(a * 18 + o) * 9 + b];
        }
    }

    // ---------------- stage 3: acc(ch) = sum_ij e*W[ij*16+2g] + o*W[ij*16+2g+1] ----------------
    for (int q = 0; q < 32; ++q) {
        const int ch0 = q * 8;
        // stage both frames: 24 slabs (fr, tr, half4), 6 per wave
        #pragma unroll
        for (int k = 0; k < 6; ++k) {
            const int s = wv + 4 * k;          // 0..23
            const int fr = s / 12, rm = s % 12;
            const int tr = rm >> 1, half = rm & 1;
            if (lane < 58) {
                const float* src = (fr ? xo : xe) + (size_t)(ch0 + half * 4) * HW + srow[tr];
                float4 v;
                v.x = src[0]; v.y = src[HW]; v.z = src[2 * HW]; v.w = src[3 * HW];
                *(float4*)&tile[fr][tr][lane][half * 4] = v;
            }
        }
        __syncthreads();

        float acc[8];
        #pragma unroll
        for (int cc = 0; cc < 8; ++cc) acc[cc] = 0.f;
        #pragma unroll
        for (int di = 0; di < 3; ++di)
            #pragma unroll
            for (int dj = 0; dj < 3; ++dj) {
                const int ij = di * 3 + dj;
                const float* pe = &tile[0][wv + di][col + dj][0];
                const float* po = &tile[1][wv + di][col + dj][0];
                const float4 e0 = *(const float4*)pe;
                const float4 e1 = *(const float4*)(pe + 4);
                const float4 o0 = *(const float4*)po;
                const float4 o1 = *(const float4*)(po + 4);
                acc[0] += e0.x * Wv[ij * 16 + 0]  + o0.x * Wv[ij * 16 + 1];
                acc[1] += e0.y * Wv[ij * 16 + 2]  + o0.y * Wv[ij * 16 + 3];
                acc[2] += e0.z * Wv[ij * 16 + 4]  + o0.z * Wv[ij * 16 + 5];
                acc[3] += e0.w * Wv[ij * 16 + 6]  + o0.w * Wv[ij * 16 + 7];
                acc[4] += e1.x * Wv[ij * 16 + 8]  + o1.x * Wv[ij * 16 + 9];
                acc[5] += e1.y * Wv[ij * 16 + 10] + o1.y * Wv[ij * 16 + 11];
                acc[6] += e1.z * Wv[ij * 16 + 12] + o1.z * Wv[ij * 16 + 13];
                acc[7] += e1.w * Wv[ij * 16 + 14] + o1.w * Wv[ij * 16 + 15];
            }

        #pragma unroll
        for (int cc = 0; cc < 8; ++cc) {
            if (act) out[((size_t)n * 256 + ch0 + cc) * HW + r * WID + lane] = acc[cc];
            sred[cc][t] = act ? acc[cc] : 0.f;
        }
        __syncthreads();
        {   // per-(block, channel) partials; strided b32 reads -> conflict-free
            const int c2 = t >> 5, sg = t & 31;
            float s = 0.f, qq = 0.f;
            #pragma unroll
            for (int k = 0; k < 8; ++k) {
                const float v = sred[c2][sg + 32 * k];
                s += v; qq += v * v;
            }
            #pragma unroll
            for (int o = 16; o >= 1; o >>= 1) {
                s  += __shfl_xor(s, o);
                qq += __shfl_xor(qq, o);
            }
            if (sg == 0) {
                psum  [(ch0 + c2) * 448 + blk] = s;
                psumsq[(ch0 + c2) * 448 + blk] = qq;
            }
        }
        // next iteration's __syncthreads (after staging) separates sred reads from rewrites
    }
}

__global__ void tf_stats(const float* __restrict__ ps, const float* __restrict__ pq,
                         const float* __restrict__ gamma, const float* __restrict__ beta,
                         float* __restrict__ AB)
{
    const int ch = blockIdx.x;
    const int l = threadIdx.x;
    float s = 0.f, q = 0.f;
    for (int b = l; b < 448; b += 64) {
        s += ps[ch * 448 + b];
        q += pq[ch * 448 + b];
    }
    #pragma unroll
    for (int o = 32; o >= 1; o >>= 1) {
        s += __shfl_xor(s, o);
        q += __shfl_xor(q, o);
    }
    if (l == 0) {
        const float inv = 1.f / 100352.f;   // nt2*h*w
        const float mean = s * inv;
        const float var = q * inv - mean * mean;
        const float rstd = rsqrtf(var + 1e-5f);
        const float A = gamma[ch] * rstd;
        AB[ch] = A;
        AB[256 + ch] = beta[ch] - mean * A;
    }
}

__global__ void tf_norm(float* __restrict__ out, const float* __restrict__ AB)
{
    const unsigned total4 = 32u * 256u * 784u;  // 6,422,528 float4
    unsigned i = blockIdx.x * 256u + threadIdx.x;
    const unsigned stride = gridDim.x * 256u;
    float4* o4 = (float4*)out;
    for (; i < total4; i += stride) {
        const unsigned ch = (i / 784u) & 255u;
        const float A = AB[ch], B = AB[256 + ch];
        float4 v = o4[i];
        v.x = v.x * A + B;
        v.y = v.y * A + B;
        v.z = v.z * A + B;
        v.w = v.w * A + B;
        o4[i] = v;
    }
}

extern "C" void kernel_launch(void* const* d_in, const int* in_sizes, int n_in,
                              void* d_out, int out_size, void* d_ws, size_t ws_size,
                              hipStream_t stream) {
    const float* x     = (const float*)d_in[0];
    const float* wconv = (const float*)d_in[1];
    const float* bconv = (const float*)d_in[2];
    const float* gamma = (const float*)d_in[3];
    const float* beta  = (const float*)d_in[4];
    float* out = (float*)d_out;

    float* psum   = (float*)d_ws;            // [256][448]
    float* psumsq = psum + 256 * 448;        // [256][448]
    float* AB     = psumsq + 256 * 448;      // [512]

    tf_fused<<<448, 256, 0, stream>>>(x, wconv, bconv, out, psum, psumsq);
    tf_stats<<<256, 64, 0, stream>>>(psum, psumsq, gamma, beta, AB);
    tf_norm<<<2048, 256, 0, stream>>>(out, AB);
}

// Round 3
// 583.141 us; speedup vs baseline: 2.9233x; 2.0217x over previous
//
#include <hip/hip_runtime.h>
#include <cstdint>

#define HW 3136
#define WID 56
#define NBLK 1792   // 32 frame-pairs * 56 rows

__device__ __forceinline__ int clampi(int v, int lo, int hi) {
    return v < lo ? lo : (v > hi ? hi : v);
}

// Block = 1 output row of one frame-pair (56 px). 256 threads = 4 waves.
// Wave s handles channels cc = {2s, 2s+1} of each 8-channel chunk.
// LDS: Wl[144][56] (per-pixel W, computed cooperatively), tile[2][3][58][12]
// (phase1: [buf] odd-frame dbuf; phase3: [frame] single-buf), CP[4][9][56]
// (cross-slice corr reduce). Total 57024 B static -> 2 blocks/CU.
// No thread ever holds >36 W values -> no spill by construction.
__global__ __launch_bounds__(256, 2) void tf_fused(
    const float* __restrict__ x, const float* __restrict__ wconv,
    const float* __restrict__ bconv, float* __restrict__ out,
    float* __restrict__ psum, float* __restrict__ psumsq)
{
    __shared__ float Wl[144 * 56];          // [f][px]
    __shared__ float TL[2 * 3 * 58 * 12];   // [buf|fr][row][col][ch(8,pad12)]
    __shared__ float CP[4 * 9 * 56];        // [slice][ij][px]

    const int blk = blockIdx.x;
    const int n  = blk / 56;
    const int r0 = blk % 56;
    const int t = threadIdx.x;
    const int s = t >> 6;          // wave == channel-slice 0..3
    const int lane = t & 63;
    const bool act = lane < WID;
    const int px = act ? lane : (WID - 1);

    const float* xe = x + (size_t)(2 * n) * 256 * HW;
    const float* xo = xe + (size_t)256 * HW;

    const int sc = clampi(lane - 1, 0, 55);
    int srow[3];
    #pragma unroll
    for (int tr = 0; tr < 3; ++tr) srow[tr] = clampi(r0 + tr - 1, 0, 55) * WID + sc;

    // ---- W init: Wl[f][px] = bconv[f]; wave-uniform f -> scalar loads ----
    if (act) {
        #pragma unroll
        for (int k = 0; k < 36; ++k) {
            const int f = s * 36 + k;
            Wl[f * 56 + px] = bconv[f];
        }
    }

    // ---- staging lambdas (ch-pad 12: b128 writes / b64 reads conflict-free) ----
    auto stage1 = [&](int buf, int ch0) {   // odd frame only, into [buf]
        #pragma unroll
        for (int k = 0; k < 2; ++k) {
            const int sl = s + 4 * k;       // 0..7, use 0..5
            if (sl < 6 && lane < 58) {
                const int tr = sl >> 1, half = sl & 1;
                const float* src = xo + (size_t)(ch0 + half * 4) * HW + srow[tr];
                float4 v;
                v.x = src[0]; v.y = src[HW]; v.z = src[2 * HW]; v.w = src[3 * HW];
                *(float4*)&TL[((buf * 3 + tr) * 58 + lane) * 12 + half * 4] = v;
            }
        }
    };
    auto stage3 = [&](int ch0) {            // both frames: [fr]
        #pragma unroll
        for (int k = 0; k < 3; ++k) {
            const int sl = s + 4 * k;       // 0..11
            const int fr = (sl >= 6) ? 1 : 0;
            const int rm = sl - 6 * fr;
            const int tr = rm >> 1, half = rm & 1;
            if (lane < 58) {
                const float* src = (fr ? xo : xe) + (size_t)(ch0 + half * 4) * HW + srow[tr];
                float4 v;
                v.x = src[0]; v.y = src[HW]; v.z = src[2 * HW]; v.w = src[3 * HW];
                *(float4*)&TL[((fr * 3 + tr) * 58 + lane) * 12 + half * 4] = v;
            }
        }
    };

    // ================= phase 1: corr partials -> fold into Wl =================
    const float* xer = xe + r0 * WID + px;

    stage1(0, 0);
    __syncthreads();

    for (int g = 0; g < 8; ++g) {
        float crg[9];
        #pragma unroll
        for (int i = 0; i < 9; ++i) crg[i] = 0.f;

        #pragma unroll
        for (int sub = 0; sub < 4; ++sub) {
            const int q = g * 4 + sub;
            const int buf = q & 1;
            if (q < 31) stage1(buf ^ 1, (q + 1) * 8);

            const float e0 = xer[(size_t)(q * 8 + 2 * s) * HW];
            const float e1 = xer[(size_t)(q * 8 + 2 * s + 1) * HW];

            #pragma unroll
            for (int di = 0; di < 3; ++di)
                #pragma unroll
                for (int dj = 0; dj < 3; ++dj) {
                    const float2 o = *(const float2*)
                        &TL[((buf * 3 + di) * 58 + px + dj) * 12 + 2 * s];
                    crg[di * 3 + dj] += e0 * o.x + e1 * o.y;
                }

            if (sub == 3 && act) {
                #pragma unroll
                for (int ij = 0; ij < 9; ++ij) CP[(s * 9 + ij) * 56 + px] = crg[ij];
            }
            __syncthreads();
        }

        // fold group g into Wl (after barrier: all CP published)
        {
            float cf[9];
            #pragma unroll
            for (int ij = 0; ij < 9; ++ij)
                cf[ij] = CP[(0 * 9 + ij) * 56 + px] + CP[(1 * 9 + ij) * 56 + px]
                       + CP[(2 * 9 + ij) * 56 + px] + CP[(3 * 9 + ij) * 56 + px];
            if (act) {
                const int o0 = (9 * s + 1) >> 1;        // {0,5,9,14}
                const int o1 = (9 * (s + 1) + 1) >> 1;  // {5,9,14,18}
                #pragma unroll
                for (int ij = 0; ij < 9; ++ij) {
                    const int F = ij * 8 + g, a = F / 9, b = F % 9;
                    const float c = cf[ij];
                    for (int o = o0; o < o1; ++o) {
                        const int f = a * 18 + o;
                        Wl[f * 56 + px] += c * wconv[f * 9 + b];
                    }
                }
            }
        }
        // next CP rewrite is >=4 barriers away -> safe without extra barrier
    }
    __syncthreads();   // all folds complete before Wl reads / tile reuse

    // ---- hoist this thread's 36 q-invariant W values into registers ----
    float Wv[9][4];
    #pragma unroll
    for (int ij = 0; ij < 9; ++ij)
        #pragma unroll
        for (int j = 0; j < 4; ++j)
            Wv[ij][j] = Wl[(ij * 16 + 4 * s + j) * 56 + px];

    // ================= phase 3: weighted gather + BN partials =================
    for (int q = 0; q < 32; ++q) {
        stage3(q * 8);
        __syncthreads();

        float a0 = 0.f, a1 = 0.f;
        #pragma unroll
        for (int di = 0; di < 3; ++di)
            #pragma unroll
            for (int dj = 0; dj < 3; ++dj) {
                const int ij = di * 3 + dj;
                const float2 e = *(const float2*)
                    &TL[((0 * 3 + di) * 58 + px + dj) * 12 + 2 * s];
                const float2 o = *(const float2*)
                    &TL[((1 * 3 + di) * 58 + px + dj) * 12 + 2 * s];
                a0 += e.x * Wv[ij][0] + o.x * Wv[ij][1];
                a1 += e.y * Wv[ij][2] + o.y * Wv[ij][3];
            }

        const int ch = q * 8 + 2 * s;
        if (act) {
            out[((size_t)n * 256 + ch) * HW + r0 * WID + lane] = a0;
            out[((size_t)n * 256 + ch + 1) * HW + r0 * WID + lane] = a1;
        } else {
            a0 = 0.f; a1 = 0.f;
        }

        // BN partials: wave covers the 56 px of this row for 2 channels
        float s0 = a0, q0 = a0 * a0, s1 = a1, q1 = a1 * a1;
        #pragma unroll
        for (int off = 32; off >= 1; off >>= 1) {
            s0 += __shfl_xor(s0, off); q0 += __shfl_xor(q0, off);
            s1 += __shfl_xor(s1, off); q1 += __shfl_xor(q1, off);
        }
        if (lane == 0) {
            psum  [(size_t)ch * NBLK + blk] = s0;
            psumsq[(size_t)ch * NBLK + blk] = q0;
            psum  [(size_t)(ch + 1) * NBLK + blk] = s1;
            psumsq[(size_t)(ch + 1) * NBLK + blk] = q1;
        }
        __syncthreads();   // tile reuse next q
    }
}

__global__ void tf_stats(const float* __restrict__ ps, const float* __restrict__ pq,
                         const float* __restrict__ gamma, const float* __restrict__ beta,
                         float* __restrict__ AB)
{
    const int ch = blockIdx.x;
    const int l = threadIdx.x;
    float s = 0.f, q = 0.f;
    for (int b = l; b < NBLK; b += 64) {
        s += ps[(size_t)ch * NBLK + b];
        q += pq[(size_t)ch * NBLK + b];
    }
    #pragma unroll
    for (int o = 32; o >= 1; o >>= 1) {
        s += __shfl_xor(s, o);
        q += __shfl_xor(q, o);
    }
    if (l == 0) {
        const float inv = 1.f / 100352.f;   // nt2*h*w
        const float mean = s * inv;
        const float var = q * inv - mean * mean;
        const float rstd = rsqrtf(var + 1e-5f);
        const float A = gamma[ch] * rstd;
        AB[ch] = A;
        AB[256 + ch] = beta[ch] - mean * A;
    }
}

__global__ void tf_norm(float* __restrict__ out, const float* __restrict__ AB)
{
    const unsigned total4 = 32u * 256u * 784u;  // 6,422,528 float4
    unsigned i = blockIdx.x * 256u + threadIdx.x;
    const unsigned stride = gridDim.x * 256u;
    float4* o4 = (float4*)out;
    for (; i < total4; i += stride) {
        const unsigned ch = (i / 784u) & 255u;
        const float A = AB[ch], B = AB[256 + ch];
        float4 v = o4[i];
        v.x = v.x * A + B;
        v.y = v.y * A + B;
        v.z = v.z * A + B;
        v.w = v.w * A + B;
        o4[i] = v;
    }
}

extern "C" void kernel_launch(void* const* d_in, const int* in_sizes, int n_in,
                              void* d_out, int out_size, void* d_ws, size_t ws_size,
                              hipStream_t stream) {
    const float* x     = (const float*)d_in[0];
    const float* wconv = (const float*)d_in[1];
    const float* bconv = (const float*)d_in[2];
    const float* gamma = (const float*)d_in[3];
    const float* beta  = (const float*)d_in[4];
    float* out = (float*)d_out;

    float* psum   = (float*)d_ws;                 // [256][1792]
    float* psumsq = psum + 256 * NBLK;            // [256][1792]
    float* AB     = psumsq + 256 * NBLK;          // [512]

    tf_fused<<<NBLK, 256, 0, stream>>>(x, wconv, bconv, out, psum, psumsq);
    tf_stats<<<256, 64, 0, stream>>>(psum, psumsq, gamma, beta, AB);
    tf_norm<<<2048, 256, 0, stream>>>(out, AB);
}

// Round 4
// 469.201 us; speedup vs baseline: 3.6332x; 1.2428x over previous
//
#include <hip/hip_runtime.h>
#include <cstdint>

#define HW 3136
#define WID 56
#define NBLK 1792   // 32 frame-pairs * 56 rows
#define TSZ 2088    // one frame tile [3 rows][58 cols][12 ch-pad] floats
// S layout (floats):
//  [0,2088)      tile region 0: phase1 dbuf0 / phase3 bufA fr0
//  [2088,4176)   tile region 1: phase1 dbuf1 / phase3 bufA fr1
//  [4176,8208)   CR[72][56]   ; phase3 bufB fr0 @4176, fr1 @6264 (CR/CP dead by then)
//  [8208,10224)  CP[4][9][56]
#define CR_OFF 4176
#define CP_OFF 8208
#define SFLOATS 10224   // 40896 B -> rounds to 40960 -> exactly 4 blocks/CU

__device__ __forceinline__ int clampi(int v, int lo, int hi) {
    return v < lo ? lo : (v > hi ? hi : v);
}

// Block = 1 output row of one frame-pair (56 px), 256 thr = 4 waves.
// Wave s owns channels {2s,2s+1} of each 8-channel chunk.
// Phase1: corr partials -> CP -> CR[72][56]. W hoist: 36 regs/thread from CR.
// Phase3: double-buffered async-split staging, 18 b64 LDS reads + 36 FMA per q.
__global__ __launch_bounds__(256, 4) void tf_fused(
    const float* __restrict__ x, const float* __restrict__ wconv,
    const float* __restrict__ bconv, float* __restrict__ out,
    float* __restrict__ psum, float* __restrict__ psumsq)
{
    __shared__ float S[SFLOATS];

    const int d = blockIdx.x;
    const int logical = (d & 7) * 224 + (d >> 3);   // XCD x owns frame-pairs 4x..4x+3
    const int n  = logical / 56;
    const int r0 = logical % 56;
    const int t = threadIdx.x;
    const int su = __builtin_amdgcn_readfirstlane(t >> 6);  // wave slice, provably uniform
    const int lane = t & 63;
    const bool act = lane < WID;
    const int px = act ? lane : (WID - 1);

    const float* xe = x + (size_t)(2 * n) * 256 * HW;
    const float* xo = xe + (size_t)256 * HW;

    const int sc = clampi(lane - 1, 0, 55);
    int srow[3];
    #pragma unroll
    for (int tr = 0; tr < 3; ++tr) srow[tr] = clampi(r0 + tr - 1, 0, 55) * WID + sc;

    float st[3][4];   // staged regs (async-split)

    // ---- staging helpers; ch-slot rotated by 2 when (col>>3)&1 -> b64 reads hit 32 banks ----
    auto stage1L = [&](int ch0) {               // odd frame, 6 slabs
        #pragma unroll
        for (int k = 0; k < 2; ++k) {
            const int sl = su + 4 * k;
            if (sl < 6 && lane < 58) {
                const int tr = sl >> 1, half = sl & 1;
                const float* src = xo + (size_t)(ch0 + half * 4) * HW + srow[tr];
                st[k][0] = src[0]; st[k][1] = src[HW];
                st[k][2] = src[2 * HW]; st[k][3] = src[3 * HW];
            }
        }
    };
    auto stage1W = [&](int base) {
        #pragma unroll
        for (int k = 0; k < 2; ++k) {
            const int sl = su + 4 * k;
            if (sl < 6 && lane < 58) {
                const int tr = sl >> 1, half = sl & 1;
                float4 v = make_float4(st[k][0], st[k][1], st[k][2], st[k][3]);
                if ((lane >> 3) & 1) v = make_float4(v.z, v.w, v.x, v.y);
                *(float4*)&S[base + (tr * 58 + lane) * 12 + half * 4] = v;
            }
        }
    };
    auto stage3L = [&](int ch0) {               // both frames, 12 slabs
        #pragma unroll
        for (int k = 0; k < 3; ++k) {
            const int sl = su + 4 * k;
            const int fr = (sl >= 6) ? 1 : 0;
            const int rm = sl - 6 * fr;
            const int tr = rm >> 1, half = rm & 1;
            if (lane < 58) {
                const float* src = (fr ? xo : xe) + (size_t)(ch0 + half * 4) * HW + srow[tr];
                st[k][0] = src[0]; st[k][1] = src[HW];
                st[k][2] = src[2 * HW]; st[k][3] = src[3 * HW];
            }
        }
    };
    auto stage3W = [&](int base) {
        #pragma unroll
        for (int k = 0; k < 3; ++k) {
            const int sl = su + 4 * k;
            const int fr = (sl >= 6) ? 1 : 0;
            const int rm = sl - 6 * fr;
            const int tr = rm >> 1, half = rm & 1;
            if (lane < 58) {
                float4 v = make_float4(st[k][0], st[k][1], st[k][2], st[k][3]);
                if ((lane >> 3) & 1) v = make_float4(v.z, v.w, v.x, v.y);
                *(float4*)&S[base + fr * TSZ + (tr * 58 + lane) * 12 + half * 4] = v;
            }
        }
    };
    // read the (2s,2s+1) channel pair at (tileBase, tr, col)
    auto rdpair = [&](int base, int tr, int col) -> float2 {
        const int rot = ((col >> 3) & 1) << 1;
        const int c = ((su >> 1) << 2) + ((((su & 1) << 1) + rot) & 3);
        return *(const float2*)&S[base + (tr * 58 + col) * 12 + c];
    };

    // ================= phase 1: corr -> CR =================
    const float* xer = xe + r0 * WID + px;
    float e0 = xer[(size_t)(2 * su) * HW];
    float e1 = xer[(size_t)(2 * su + 1) * HW];

    stage1L(0);
    stage1W(0);
    __syncthreads();

    for (int g = 0; g < 8; ++g) {
        float crg[9];
        #pragma unroll
        for (int i = 0; i < 9; ++i) crg[i] = 0.f;

        #pragma unroll
        for (int sub = 0; sub < 4; ++sub) {
            const int q = g * 4 + sub;
            const int bufb = q & 1;
            float e0n, e1n;
            if (q < 31) {
                stage1L((q + 1) * 8);
                e0n = xer[(size_t)((q + 1) * 8 + 2 * su) * HW];
                e1n = xer[(size_t)((q + 1) * 8 + 2 * su + 1) * HW];
            }
            #pragma unroll
            for (int di = 0; di < 3; ++di)
                #pragma unroll
                for (int dj = 0; dj < 3; ++dj) {
                    const float2 o = rdpair(bufb * TSZ, di, px + dj);
                    crg[di * 3 + dj] += e0 * o.x + e1 * o.y;
                }
            if (sub == 3 && act) {
                #pragma unroll
                for (int ij = 0; ij < 9; ++ij)
                    S[CP_OFF + (su * 9 + ij) * 56 + px] = crg[ij];
            }
            if (q < 31) stage1W((bufb ^ 1) * TSZ);
            __syncthreads();
            if (q < 31) { e0 = e0n; e1 = e1n; }
        }
        // reduce CP -> CR for this g (CP next rewritten 4 barriers away)
        for (int ij = su; ij < 9; ij += 4) {
            const float v = S[CP_OFF + (0 * 9 + ij) * 56 + px]
                          + S[CP_OFF + (1 * 9 + ij) * 56 + px]
                          + S[CP_OFF + (2 * 9 + ij) * 56 + px]
                          + S[CP_OFF + (3 * 9 + ij) * 56 + px];
            S[CR_OFF + (ij * 8 + g) * 56 + px] = v;
        }
    }
    __syncthreads();   // all CR writes visible

    // ---- hoist 36 q-invariant W values: W[f] = b[f] + sum_b CR[(f/18)*9+b]*wconv[f*9+b] ----
    float Wv[9][4];
    #pragma unroll
    for (int ij = 0; ij < 9; ++ij)
        #pragma unroll
        for (int j = 0; j < 4; ++j) {
            const int f = ij * 16 + 4 * su + j;   // uniform -> s_loads for wconv/bconv
            const int a = f / 18;
            float w = bconv[f];
            #pragma unroll
            for (int b = 0; b < 9; ++b)
                w += S[CR_OFF + (a * 9 + b) * 56 + px] * wconv[f * 9 + b];
            Wv[ij][j] = w;
        }

    // ================= phase 3: weighted gather + BN partials =================
    stage3L(0);
    stage3W(0);          // bufA; CR reads above completed before upcoming barrier
    __syncthreads();

    float* ob = out + (size_t)n * 256 * HW + r0 * WID;

    for (int q = 0; q < 32; ++q) {
        if (q < 31) stage3L((q + 1) * 8);
        const int bufoff = (q & 1) ? CR_OFF : 0;

        float a0 = 0.f, a1 = 0.f;
        #pragma unroll
        for (int di = 0; di < 3; ++di)
            #pragma unroll
            for (int dj = 0; dj < 3; ++dj) {
                const int ij = di * 3 + dj;
                const float2 e = rdpair(bufoff, di, px + dj);
                const float2 o = rdpair(bufoff + TSZ, di, px + dj);
                a0 += e.x * Wv[ij][0] + o.x * Wv[ij][1];
                a1 += e.y * Wv[ij][2] + o.y * Wv[ij][3];
            }

        if (q < 31) stage3W(((q & 1) ^ 1) ? CR_OFF : 0);

        const int ch = q * 8 + 2 * su;
        if (act) {
            ob[(size_t)ch * HW + lane] = a0;
            ob[(size_t)(ch + 1) * HW + lane] = a1;
        } else {
            a0 = 0.f; a1 = 0.f;
        }
        float s0 = a0, q0 = a0 * a0, s1 = a1, q1 = a1 * a1;
        #pragma unroll
        for (int off = 32; off >= 1; off >>= 1) {
            s0 += __shfl_xor(s0, off); q0 += __shfl_xor(q0, off);
            s1 += __shfl_xor(s1, off); q1 += __shfl_xor(q1, off);
        }
        if (lane == 0) {
            psum  [(size_t)ch * NBLK + logical] = s0;
            psumsq[(size_t)ch * NBLK + logical] = q0;
            psum  [(size_t)(ch + 1) * NBLK + logical] = s1;
            psumsq[(size_t)(ch + 1) * NBLK + logical] = q1;
        }
        __syncthreads();
    }
}

__global__ void tf_stats(const float* __restrict__ ps, const float* __restrict__ pq,
                         const float* __restrict__ gamma, const float* __restrict__ beta,
                         float* __restrict__ AB)
{
    const int ch = blockIdx.x;
    const int l = threadIdx.x;
    float s = 0.f, q = 0.f;
    for (int b = l; b < NBLK; b += 64) {
        s += ps[(size_t)ch * NBLK + b];
        q += pq[(size_t)ch * NBLK + b];
    }
    #pragma unroll
    for (int o = 32; o >= 1; o >>= 1) {
        s += __shfl_xor(s, o);
        q += __shfl_xor(q, o);
    }
    if (l == 0) {
        const float inv = 1.f / 100352.f;   // nt2*h*w
        const float mean = s * inv;
        const float var = q * inv - mean * mean;
        const float rstd = rsqrtf(var + 1e-5f);
        const float A = gamma[ch] * rstd;
        AB[ch] = A;
        AB[256 + ch] = beta[ch] - mean * A;
    }
}

__global__ void tf_norm(float* __restrict__ out, const float* __restrict__ AB)
{
    const unsigned total4 = 32u * 256u * 784u;  // 6,422,528 float4
    unsigned i = blockIdx.x * 256u + threadIdx.x;
    const unsigned stride = gridDim.x * 256u;
    float4* o4 = (float4*)out;
    for (; i < total4; i += stride) {
        const unsigned ch = (i / 784u) & 255u;
        const float A = AB[ch], B = AB[256 + ch];
        float4 v = o4[i];
        v.x = v.x * A + B;
        v.y = v.y * A + B;
        v.z = v.z * A + B;
        v.w = v.w * A + B;
        o4[i] = v;
    }
}

extern "C" void kernel_launch(void* const* d_in, const int* in_sizes, int n_in,
                              void* d_out, int out_size, void* d_ws, size_t ws_size,
                              hipStream_t stream) {
    const float* x     = (const float*)d_in[0];
    const float* wconv = (const float*)d_in[1];
    const float* bconv = (const float*)d_in[2];
    const float* gamma = (const float*)d_in[3];
    const float* beta  = (const float*)d_in[4];
    float* out = (float*)d_out;

    float* psum   = (float*)d_ws;                 // [256][1792]
    float* psumsq = psum + 256 * NBLK;            // [256][1792]
    float* AB     = psumsq + 256 * NBLK;          // [512]

    tf_fused<<<NBLK, 256, 0, stream>>>(x, wconv, bconv, out, psum, psumsq);
    tf_stats<<<256, 64, 0, stream>>>(psum, psumsq, gamma, beta, AB);
    tf_norm<<<2048, 256, 0, stream>>>(out, AB);
}